// Round 7
// baseline (16.359 us; speedup 1.0000x reference)
//
#include <hip/hip_runtime.h>

// B=32, score 128x128, images 3x512x512, region 70x70, img_stride=3.
// Crop origins are EXACT integers (idx*3+70): the reference's bilinear crop
// degenerates to a gather with zero-fill where y/x > 511.
//
// SINGLE kernel, 256 blocks x 1024 threads = 1 block/CU, 16 waves/CU.
// Block (b, chunk):
//   Phase 1: all 1024 threads scan batch b's full 16K score map (4 float4
//            each, idx-increasing per thread -> strict compares keep first
//            occurrence), wave butterfly + 16-wave LDS merge -> argmax/argmin.
//            Redundancy: 8 blocks/batch -> 16 MB total L2 traffic (~0.5 us).
//   Phase 2: this block writes 1/8 of batch b's crop work: ~2 float4 per
//            thread; fast-path single unaligned dwordx4 gather, dual float4
//            stores (primary crop + channel-concat copy).
#define SSZ   16384
#define SW    128
#define IMG   512
#define NPER  470400            // 32*3*70*70
#define OFF_AB_F 1881600        // fake_ABf base (elements)
#define OFF_AB_R 2822400        // real_ABr base
#define NF4_BATCH 14700         // 4 crops * 3 ch * 1225 float4 per batch
#define BPB   8                 // blocks per batch
#define F4_PER_BLK 1838         // ceil(14700/8)

typedef float f4v   __attribute__((ext_vector_type(4)));
typedef float f4v_u __attribute__((ext_vector_type(4), aligned(4)));

__global__ __launch_bounds__(1024)
void fused_all(const float* __restrict__ fake_B,
               const float* __restrict__ real_A,
               const float* __restrict__ score,
               float* __restrict__ out) {
    const int b     = blockIdx.x >> 3;
    const int chunk = blockIdx.x & 7;
    const int t     = threadIdx.x;

    // ---- Phase 1: full per-batch dual argmax/argmin. ----
    const float4* p4 = (const float4*)(score + (size_t)b * SSZ);
    float vmax = -__builtin_inff(); int imax = 0;
    float vmin =  __builtin_inff(); int imin = 0;
    #pragma unroll
    for (int q = 0; q < 4; ++q) {          // e increasing within thread ->
        const float4 v = p4[t + 1024 * q]; //   strict compares = 1st occur.
        const int e = (t + 1024 * q) * 4;
        if (v.x > vmax) { vmax = v.x; imax = e;     }
        if (v.y > vmax) { vmax = v.y; imax = e + 1; }
        if (v.z > vmax) { vmax = v.z; imax = e + 2; }
        if (v.w > vmax) { vmax = v.w; imax = e + 3; }
        if (v.x < vmin) { vmin = v.x; imin = e;     }
        if (v.y < vmin) { vmin = v.y; imin = e + 1; }
        if (v.z < vmin) { vmin = v.z; imin = e + 2; }
        if (v.w < vmin) { vmin = v.w; imin = e + 3; }
    }
    #pragma unroll
    for (int off = 1; off < 64; off <<= 1) {   // wave butterfly, idx tie-break
        const float mv = __shfl_xor(vmax, off); const int mi = __shfl_xor(imax, off);
        if (mv > vmax || (mv == vmax && mi < imax)) { vmax = mv; imax = mi; }
        const float nv = __shfl_xor(vmin, off); const int ni = __shfl_xor(imin, off);
        if (nv < vmin || (nv == vmin && ni < imin)) { vmin = nv; imin = ni; }
    }
    __shared__ float sv[32];
    __shared__ int   si[32];
    const int w = t >> 6;                  // wave id 0..15
    if ((t & 63) == 0) {
        sv[w]      = vmax; si[w]      = imax;
        sv[w + 16] = vmin; si[w + 16] = imin;
    }
    __syncthreads();
    float bm = sv[0];  int bi = si[0];     // every thread merges redundantly
    float nm = sv[16]; int ni = si[16];    // (uniform LDS broadcast reads)
    #pragma unroll
    for (int x = 1; x < 16; ++x) {
        if (sv[x] > bm || (sv[x] == bm && si[x] < bi)) { bm = sv[x]; bi = si[x]; }
        if (sv[x+16] < nm || (sv[x+16] == nm && si[x+16] < ni)) { nm = sv[x+16]; ni = si[x+16]; }
    }
    int rr, rc, fr, fc;
    if (bm > 0.0f) { rr = bi / SW; rc = bi % SW; } else { rr = 0; rc = 0; }
    if (nm < 1.0f) { fr = ni / SW; fc = ni % SW; } else { fr = 1; fc = 1; }
    const int row0r = rr * 3 + 70, col0r = rc * 3 + 70;
    const int row0f = fr * 3 + 70, col0f = fc * 3 + 70;

    // ---- Phase 2: this block's 1/8 slice of batch b's 4 crops + concats. ----
    const size_t srcb = (size_t)b * 3 * (IMG * IMG);
    const int e0 = chunk * F4_PER_BLK;
    const int e1 = min(e0 + F4_PER_BLK, NF4_BATCH);
    for (int e = e0 + t; e < e1; e += 1024) {
        const int k    = e / 3675;        // crop id; 3675 = 3*1225 f4/crop
        const int rem  = e - k * 3675;
        const int c    = rem / 1225;
        const int f4   = rem - c * 1225;
        const int flat = f4 * 4;          // i*70+j
        const int i0   = flat / 70;
        const int j0   = flat - i0 * 70;

        const int row0 = (k < 2) ? row0r : row0f;
        const int col0 = (k < 2) ? col0r : col0f;
        const float* sp = ((k == 0 || k == 2) ? fake_B : real_A)
                          + srcb + (size_t)c * (IMG * IMG);
        const int y = row0 + i0;
        const int x = col0 + j0;

        f4v v;
        if (j0 != 68 && y < IMG && x + 3 < IMG) {
            v = *(const f4v_u*)(sp + y * IMG + x);   // one dwordx4
        } else {
            #pragma unroll
            for (int s = 0; s < 4; ++s) {
                int i = i0, j = j0 + s;
                if (j >= 70) { j -= 70; ++i; }       // row crossing (j0 == 68)
                const int yy = row0 + i, xx = col0 + j;
                v[s] = (yy < IMG && xx < IMG) ? sp[yy * IMG + xx] : 0.0f;
            }
        }

        const size_t inner = (size_t)c * 4900 + flat;
        const size_t prim  = (size_t)k * NPER + (size_t)b * 14700 + inner;
        const size_t cb    = ((k < 2) ? (size_t)OFF_AB_R : (size_t)OFF_AB_F)
                             + (size_t)b * 29400
                             + ((k & 1) ? 0 : 3) * 4900  // A-crops ch0-2, B ch3-5
                             + inner;
        *(f4v*)(out + prim) = v;
        *(f4v*)(out + cb)   = v;
    }
}

extern "C" void kernel_launch(void* const* d_in, const int* in_sizes, int n_in,
                              void* d_out, int out_size, void* d_ws, size_t ws_size,
                              hipStream_t stream) {
    // setup_inputs order: real_B, fake_B, real_A, score_map
    const float* fake_B    = (const float*)d_in[1];
    const float* real_A    = (const float*)d_in[2];
    const float* score_map = (const float*)d_in[3];
    float* out = (float*)d_out;

    fused_all<<<32 * BPB, 1024, 0, stream>>>(fake_B, real_A, score_map, out);
}

// Round 8
// 15.888 us; speedup vs baseline: 1.0297x; 1.0297x over previous
//
#include <hip/hip_runtime.h>

// B=32, score 128x128, images 3x512x512, region 70x70, img_stride=3.
// Crop origins are EXACT integers (idx*3+70): bilinear degenerates to a
// gather with zero-fill where y/x > 511.
//
// Best-measured structure (R4, 15.93 us):
// K1: parallel first-occurrence argmax/argmin. 512 blocks x 64 threads; each
//     block reduces a 1024-element slice of one batch's score map to packed
//     u64 keys: (order_monotone_float(v) << 32) | (~idx for max / idx for min)
//     so u64 max/min == first-occurrence argmax/argmin. -> d_ws (every slot
//     rewritten every call; kernel-boundary release makes them visible to K2).
// K2: crop gather. 2048 blocks; per block: reduce 32 keys (uniform scalar
//     loads), decode coords, then float4 gather + dual nontemporal float4
//     stores (primary crop + channel-concat copy).
//
// Cross-round evidence says total time is launch/replay-overhead dominated
// (~10-12 us fixed): R2/R4/R6/R7 (one-node, two-node, scalar/vector gather,
// NT/plain stores) all land at 15.9-16.9 us vs a ~4 us data floor.
#define SSZ   16384
#define SW    128
#define IMG   512
#define NPER  470400            // 32*3*70*70
#define OFF_AB_F 1881600        // fake_ABf base (elements)
#define OFF_AB_R 2822400        // real_ABr base
#define NF4_BATCH 14700         // 4 crops * 3 ch * 1225 float4 per batch
#define CHUNKS 64
#define F4_PER_CHUNK 230        // ceil(14700/64)

typedef float f4v __attribute__((ext_vector_type(4)));
typedef unsigned long long u64;

__device__ __forceinline__ unsigned ord_f32(float v) {
    unsigned s = __float_as_uint(v);
    return (s & 0x80000000u) ? ~s : (s | 0x80000000u);
}

__global__ __launch_bounds__(64)
void localize_partial(const float* __restrict__ score, u64* __restrict__ keys) {
    const int blk = blockIdx.x;           // b*16 + sl
    const int b = blk >> 4, sl = blk & 15;
    const int t = threadIdx.x;
    const float4* p4 = (const float4*)(score + (size_t)b * SSZ + sl * 1024);

    float vmax = -__builtin_inff(); int imax = 0;
    float vmin =  __builtin_inff(); int imin = 0;
    #pragma unroll
    for (int q = 0; q < 4; ++q) {         // idx increasing per thread -> strict
        const float4 v = p4[t + 64 * q];  //   compares keep first occurrence
        const int e = sl * 1024 + (t + 64 * q) * 4;
        if (v.x > vmax) { vmax = v.x; imax = e;     }
        if (v.y > vmax) { vmax = v.y; imax = e + 1; }
        if (v.z > vmax) { vmax = v.z; imax = e + 2; }
        if (v.w > vmax) { vmax = v.w; imax = e + 3; }
        if (v.x < vmin) { vmin = v.x; imin = e;     }
        if (v.y < vmin) { vmin = v.y; imin = e + 1; }
        if (v.z < vmin) { vmin = v.z; imin = e + 2; }
        if (v.w < vmin) { vmin = v.w; imin = e + 3; }
    }
    #pragma unroll
    for (int off = 1; off < 64; off <<= 1) {  // wave butterfly, idx tie-break
        const float mv = __shfl_xor(vmax, off); const int mi = __shfl_xor(imax, off);
        if (mv > vmax || (mv == vmax && mi < imax)) { vmax = mv; imax = mi; }
        const float nv = __shfl_xor(vmin, off); const int ni = __shfl_xor(imin, off);
        if (nv < vmin || (nv == vmin && ni < imin)) { vmin = nv; imin = ni; }
    }
    if (t == 0) {
        keys[b * 32 + sl]      = ((u64)ord_f32(vmax) << 32) | (unsigned)~imax;
        keys[b * 32 + 16 + sl] = ((u64)ord_f32(vmin) << 32) | (unsigned)imin;
    }
}

__global__ __launch_bounds__(256)
void crop_kernel(const float* __restrict__ fake_B,
                 const float* __restrict__ real_A,
                 const u64* __restrict__ keys,
                 float* __restrict__ out) {
    const int blk   = blockIdx.x;         // b*CHUNKS + chunk
    const int b     = blk / CHUNKS;
    const int chunk = blk % CHUNKS;
    const int t     = threadIdx.x;

    // Reduce this batch's 32 partial keys (wave-uniform -> scalar loads).
    const u64* kb = keys + b * 32;
    u64 km = kb[0], kn = kb[16];
    #pragma unroll
    for (int s = 1; s < 16; ++s) {
        const u64 a = kb[s];      if (a > km) km = a;
        const u64 c = kb[16 + s]; if (c < kn) kn = c;
    }
    // Decode (inverse of ord_f32).
    const unsigned uh = (unsigned)(km >> 32);
    const float bmax = __uint_as_float((uh & 0x80000000u) ? (uh & 0x7FFFFFFFu) : ~uh);
    const int bimax = (int)~(unsigned)km;
    const unsigned un = (unsigned)(kn >> 32);
    const float bmin = __uint_as_float((un & 0x80000000u) ? (un & 0x7FFFFFFFu) : ~un);
    const int bimin = (int)(unsigned)kn;

    int rr, rc, fr, fc;
    if (bmax > 0.0f) { rr = bimax / SW; rc = bimax % SW; } else { rr = 0; rc = 0; }
    if (bmin < 1.0f) { fr = bimin / SW; fc = bimin % SW; } else { fr = 1; fc = 1; }
    const int row0r = rr * 3 + 70, col0r = rc * 3 + 70;
    const int row0f = fr * 3 + 70, col0f = fc * 3 + 70;

    // This chunk's float4-slice of all 4 crops + concat copies.
    const size_t srcb = (size_t)b * 3 * (IMG * IMG);
    const int e0 = chunk * F4_PER_CHUNK;
    const int e1 = min(e0 + F4_PER_CHUNK, NF4_BATCH);
    for (int e = e0 + t; e < e1; e += 256) {
        const int k    = e / 3675;        // crop id; 3675 = 3*1225 f4/crop
        const int rem  = e - k * 3675;
        const int c    = rem / 1225;
        const int f4   = rem - c * 1225;
        const int flat = f4 * 4;          // i*70+j
        const int i0   = flat / 70;
        const int j0   = flat - i0 * 70;

        const int row0 = (k < 2) ? row0r : row0f;
        const int col0 = (k < 2) ? col0r : col0f;
        const float* sp = ((k == 0 || k == 2) ? fake_B : real_A)
                          + srcb + (size_t)c * (IMG * IMG);
        f4v v;
        #pragma unroll
        for (int s = 0; s < 4; ++s) {
            int i = i0, j = j0 + s;
            if (j >= 70) { j -= 70; ++i; }   // row crossing (j0 == 68)
            const int y = row0 + i, x = col0 + j;
            v[s] = (y < IMG && x < IMG) ? sp[y * IMG + x] : 0.0f;
        }

        const size_t inner = (size_t)c * 4900 + flat;
        const size_t prim  = (size_t)k * NPER + (size_t)b * 14700 + inner;
        const size_t cb    = ((k < 2) ? (size_t)OFF_AB_R : (size_t)OFF_AB_F)
                             + (size_t)b * 29400
                             + ((k & 1) ? 0 : 3) * 4900  // A-crops ch0-2, B ch3-5
                             + inner;
        __builtin_nontemporal_store(v, (f4v*)(out + prim));
        __builtin_nontemporal_store(v, (f4v*)(out + cb));
    }
}

extern "C" void kernel_launch(void* const* d_in, const int* in_sizes, int n_in,
                              void* d_out, int out_size, void* d_ws, size_t ws_size,
                              hipStream_t stream) {
    // setup_inputs order: real_B, fake_B, real_A, score_map
    const float* fake_B    = (const float*)d_in[1];
    const float* real_A    = (const float*)d_in[2];
    const float* score_map = (const float*)d_in[3];
    float* out  = (float*)d_out;
    u64*   keys = (u64*)d_ws;

    localize_partial<<<32 * 16, 64, 0, stream>>>(score_map, keys);
    crop_kernel<<<32 * CHUNKS, 256, 0, stream>>>(fake_B, real_A, keys, out);
}